// Round 11
// baseline (39356.781 us; speedup 1.0000x reference)
//
#include <hip/hip_runtime.h>
#include <math.h>

// LSTM_53171695124900: 2-layer LSTM, H=1024, I=64, O=2, T=4096.
// Round-11 vs round-10 (7.48ms, 1.82us/phase): the floor was the serial
// phase chain with 3 __syncthreads + cross-wave gate combine. Redesign:
// wave-specialized, BARRIER-FREE phase.
//   waves 0-3 = layer-1, one unit/wave: 4 gate-rows x 16 lanes x 64 elems.
//     wave0 polls full h1(p-1) (16 u64/lane), packs f16, relays via LDS +
//     monotone LDS flag; waves1-3 spin (one-way, no barrier). Reduce via
//     shfl_xor(1,2,4,8); gate combine via shfl_xor(16,32) IN-WAVE; publish.
//   waves 4-7 = layer-2 (W2.h1 + W3.h2), h2 polled/relayed by wave4 (flag2);
//     2-phase slack keeps it off the pacemaker.
//   W1: 32KB LDS, W2/W3: 64KB LDS, [j*256+lane] conflict-free; relay rows
//     padded stride-36 u32 (<=2-way). Relay overwrite guarded by cumulative
//     LDS done-counters. IC protocol/tags/memset/epilogue = r6-r10 (proven).

#define HID 1024
#define DIN 64
#define TSTEPS 4096
#define NWG 256
#define TPB 512

typedef unsigned long long u64;
typedef unsigned int u32;
typedef _Float16 f16x2 __attribute__((ext_vector_type(2)));
typedef __fp16   g16x2 __attribute__((ext_vector_type(2)));

// ws layout in u64: [0,2048) h1 pairs (2 slots x 1024); [2048,...) h2 rows
#define H2_OFF 2048
#define WS_NEED_U64 (2048ull + 4097ull * 1024ull)
#define WS_NEED_BYTES (WS_NEED_U64 * 8ull)
#define WS_ZERO_BYTES 32768

// dynamic LDS (bytes): W1 32KB | W23 64KB | h1relay 576 u32 | h2relay 576 u32
#define W1_OFF 0
#define W23_OFF 32768
#define H1R_OFF (32768 + 65536)
#define H2R_OFF (H1R_OFF + 576 * 4)
#define DYN_LDS_BYTES (H2R_OFF + 576 * 4)

#define GPOLL (1 << 17)
#define GLDS  (1 << 20)

__device__ __forceinline__ float sigmoid_f(float v) {
    return 1.0f / (1.0f + __expf(-v));
}
__device__ __forceinline__ float tanh_f(float v) {
    return 2.0f / (1.0f + __expf(-2.0f * v)) - 1.0f;
}

__device__ __forceinline__ void st_pair(u64* p, float h, u32 tag) {
    u64 pk = ((u64)tag << 32) | (u64)__float_as_uint(h);
    __hip_atomic_store(p, pk, __ATOMIC_RELAXED, __HIP_MEMORY_SCOPE_AGENT);
}
__device__ __forceinline__ u64 ld_pair(const u64* p) {
    return __hip_atomic_load(p, __ATOMIC_RELAXED, __HIP_MEMORY_SCOPE_AGENT);
}
#define PTAG(v) ((u32)((v) >> 32))
#define PVAL(v) (__uint_as_float((u32)(v)))

union U32H2 { u32 u; f16x2 h; g16x2 g; };
__device__ __forceinline__ u32 pk2(float a, float b) {
    U32H2 t; t.g = __builtin_amdgcn_cvt_pkrtz(a, b); return t.u;
}
__device__ __forceinline__ float dot2f(u32 a, u32 b, float c) {
    U32H2 x, y; x.u = a; y.u = b;
    return __builtin_amdgcn_fdot2(x.h, y.h, c, false);
}

// LDS flag helpers (workgroup scope)
__device__ __forceinline__ u32 lds_ld(const u32* p) {
    return __hip_atomic_load(p, __ATOMIC_RELAXED, __HIP_MEMORY_SCOPE_WORKGROUP);
}
__device__ __forceinline__ void lds_st(u32* p, u32 v) {
    __hip_atomic_store(p, v, __ATOMIC_RELAXED, __HIP_MEMORY_SCOPE_WORKGROUP);
}
__device__ __forceinline__ void lds_add(u32* p, u32 v) {
    __hip_atomic_fetch_add(p, v, __ATOMIC_RELAXED, __HIP_MEMORY_SCOPE_WORKGROUP);
}
#define LGKM0() asm volatile("s_waitcnt lgkmcnt(0)" ::: "memory")

// poll 16 tagged u64s until all tags==want; return packed f16 payload
struct PK8 { uint4 a, b; };
__device__ __forceinline__ PK8 poll16(const u64* bp, u32 want) {
    u64 t0,t1,t2,t3,t4,t5,t6,t7,t8,t9,tA,tB,tC,tD,tE,tF;
    int guard = 0;
    for (;;) {
        t0=ld_pair(bp+0);  t1=ld_pair(bp+1);  t2=ld_pair(bp+2);  t3=ld_pair(bp+3);
        t4=ld_pair(bp+4);  t5=ld_pair(bp+5);  t6=ld_pair(bp+6);  t7=ld_pair(bp+7);
        t8=ld_pair(bp+8);  t9=ld_pair(bp+9);  tA=ld_pair(bp+10); tB=ld_pair(bp+11);
        tC=ld_pair(bp+12); tD=ld_pair(bp+13); tE=ld_pair(bp+14); tF=ld_pair(bp+15);
        u32 ok = (PTAG(t0)==want)&(PTAG(t1)==want)&(PTAG(t2)==want)&(PTAG(t3)==want)
               & (PTAG(t4)==want)&(PTAG(t5)==want)&(PTAG(t6)==want)&(PTAG(t7)==want)
               & (PTAG(t8)==want)&(PTAG(t9)==want)&(PTAG(tA)==want)&(PTAG(tB)==want)
               & (PTAG(tC)==want)&(PTAG(tD)==want)&(PTAG(tE)==want)&(PTAG(tF)==want);
        if (ok) break;
        if (++guard > GPOLL) break;  // hang insurance only
    }
    PK8 r;
    r.a = make_uint4(pk2(PVAL(t0),PVAL(t1)), pk2(PVAL(t2),PVAL(t3)),
                     pk2(PVAL(t4),PVAL(t5)), pk2(PVAL(t6),PVAL(t7)));
    r.b = make_uint4(pk2(PVAL(t8),PVAL(t9)), pk2(PVAL(tA),PVAL(tB)),
                     pk2(PVAL(tC),PVAL(tD)), pk2(PVAL(tE),PVAL(tF)));
    return r;
}

#define D4(acc0, acc1, HV, WV) do { \
    acc0 = dot2f((HV).x, (WV).x, acc0); acc1 = dot2f((HV).y, (WV).y, acc1); \
    acc0 = dot2f((HV).z, (WV).z, acc0); acc1 = dot2f((HV).w, (WV).w, acc1); \
} while (0)

__global__ void
__attribute__((amdgpu_flat_work_group_size(TPB, TPB), amdgpu_waves_per_eu(2, 2)))
lstm_persistent(
    const float* __restrict__ x,
    const float* __restrict__ Wih1, const float* __restrict__ Whh1,
    const float* __restrict__ bih1, const float* __restrict__ bhh1,
    const float* __restrict__ Wih2, const float* __restrict__ Whh2,
    const float* __restrict__ bih2, const float* __restrict__ bhh2,
    const float* __restrict__ Wout, const float* __restrict__ bout,
    float* __restrict__ out, u64* __restrict__ ws, int use_hist)
{
    const int wg   = blockIdx.x;
    const int tid  = threadIdx.x;
    const int wave = tid >> 6;           // 0-3: layer1 unit; 4-7: layer2 unit
    const int lane = tid & 63;
    const int g    = lane >> 4;          // gate row within unit
    const int c16  = lane & 15;          // 64-elem chunk index
    const int uloc = wave & 3;           // unit within WG
    const int unit = (wg << 2) + uloc;
    const int row  = g * HID + unit;     // this lane's gate row

    u64* h1t = ws;
    u64* h2t = ws + H2_OFF;

    extern __shared__ __align__(16) char smem[];
    uint4* w1lds  = (uint4*)(smem + W1_OFF);    // [j*256 + tid(<256)]
    uint4* w23lds = (uint4*)(smem + W23_OFF);   // [j*256 + (tid-256)]
    u32*   h1r    = (u32*)(smem + H1R_OFF);     // padded 576
    u32*   h2r    = (u32*)(smem + H2R_OFF);

    __shared__ u32 flag1, flag2, done1, done2;
    __shared__ float red0[8], red1[8];
    if (tid == 0) { flag1 = 0; flag2 = 0; done1 = 0; done2 = 0; }

    // ---- one-time weight staging (f16, conflict-free [j*256+idx]) ----
    if (tid < 256) {
        const float* src = Whh1 + (size_t)row * HID + (c16 << 6);
        #pragma unroll
        for (int j = 0; j < 8; ++j) {
            float4 qa = *(const float4*)(src + 8*j);
            float4 qb = *(const float4*)(src + 8*j + 4);
            w1lds[j*256 + tid] = make_uint4(pk2(qa.x,qa.y), pk2(qa.z,qa.w),
                                            pk2(qb.x,qb.y), pk2(qb.z,qb.w));
        }
    } else {
        const int idx2 = tid - 256;
        const float* s2 = Wih2 + (size_t)row * HID + (c16 << 6);
        const float* s3 = Whh2 + (size_t)row * HID + (c16 << 6);
        #pragma unroll
        for (int j = 0; j < 8; ++j) {
            float4 qa = *(const float4*)(s2 + 8*j);
            float4 qb = *(const float4*)(s2 + 8*j + 4);
            w23lds[j*256 + idx2] = make_uint4(pk2(qa.x,qa.y), pk2(qa.z,qa.w),
                                              pk2(qb.x,qb.y), pk2(qb.z,qb.w));
        }
        #pragma unroll
        for (int j = 0; j < 8; ++j) {
            float4 qa = *(const float4*)(s3 + 8*j);
            float4 qb = *(const float4*)(s3 + 8*j + 4);
            w23lds[(8+j)*256 + idx2] = make_uint4(pk2(qa.x,qa.y), pk2(qa.z,qa.w),
                                                  pk2(qb.x,qb.y), pk2(qb.z,qb.w));
        }
    }

    // loop invariants
    const float bsum1 = bih1[row] + bhh1[row];
    const float bsum2 = bih2[row] + bhh2[row];
    const float4 wx = *(const float4*)(Wih1 + (size_t)row * DIN + (c16 << 2));
    const int rdofs = 36 * c16;                      // relay read base (u32)
    const int wrofs = 8 * lane + ((lane >> 2) << 2); // relay write base (u32)
    float cst = 0.0f;                                // c1 (waves 0-3) / c2 (4-7)

    __syncthreads();   // weights staged, flags zeroed (only barrier until epilogue)

    for (int p = 0; p <= TSTEPS; ++p) {
        const u32 pw = (u32)p;

        if (wave < 4) {
            // ================= layer 1 (pacemaker) =================
            if (wave == 0) {
                PK8 pk = poll16(h1t + (size_t)(p & 1) * 1024 + (lane << 4), pw);
                // readers of previous relay must be done before overwrite
                { int gd = 0;
                  while (lds_ld(&done1) < 7u * pw) { if (++gd > GLDS) break; } }
                *(uint4*)(h1r + wrofs)     = pk.a;
                *(uint4*)(h1r + wrofs + 4) = pk.b;
                LGKM0();
                if (lane == 0) lds_st(&flag1, pw + 1);
            } else {
                int gd = 0;
                while (lds_ld(&flag1) < pw + 1) { if (++gd > GLDS) break; }
            }
            // read h1 chunk [64*c16, +64)
            const u32* rb = h1r + rdofs;
            uint4 h0 = *(const uint4*)(rb + 0),  h1v = *(const uint4*)(rb + 4);
            uint4 h2v = *(const uint4*)(rb + 8), h3v = *(const uint4*)(rb + 12);
            uint4 h4v = *(const uint4*)(rb + 16), h5v = *(const uint4*)(rb + 20);
            uint4 h6v = *(const uint4*)(rb + 24), h7v = *(const uint4*)(rb + 28);
            if (wave != 0) { LGKM0(); if (lane == 0) lds_add(&done1, 1); }

            float a0 = (c16 == 0) ? bsum1 : 0.0f, a1 = 0.0f;
            D4(a0, a1, h0, w1lds[0*256 + tid]);
            D4(a0, a1, h1v, w1lds[1*256 + tid]);
            D4(a0, a1, h2v, w1lds[2*256 + tid]);
            D4(a0, a1, h3v, w1lds[3*256 + tid]);
            D4(a0, a1, h4v, w1lds[4*256 + tid]);
            D4(a0, a1, h5v, w1lds[5*256 + tid]);
            D4(a0, a1, h6v, w1lds[6*256 + tid]);
            D4(a0, a1, h7v, w1lds[7*256 + tid]);
            {   const int tx = (p < TSTEPS) ? p : 0;
                const float4 xv = *(const float4*)(x + (size_t)tx * DIN + (c16 << 2));
                a0 = fmaf(wx.x, xv.x, a0); a1 = fmaf(wx.y, xv.y, a1);
                a0 = fmaf(wx.z, xv.z, a0); a1 = fmaf(wx.w, xv.w, a1); }
            float s = a0 + a1;
            s += __shfl_xor(s, 1); s += __shfl_xor(s, 2);
            s += __shfl_xor(s, 4); s += __shfl_xor(s, 8);
            float sB = __shfl_xor(s, 16);
            float sC = __shfl_xor(s, 32);
            float sD = __shfl_xor(sB, 32);
            // valid on g==0 lanes: s=i, sB=f, sC=g, sD=o
            float iv = sigmoid_f(s), fv = sigmoid_f(sB);
            float gv = tanh_f(sC),  ov = sigmoid_f(sD);
            cst = fv * cst + iv * gv;
            float hv = ov * tanh_f(cst);
            if (p < TSTEPS && lane == 0)
                st_pair(h1t + (size_t)((p + 1) & 1) * 1024 + unit, hv, pw + 1);
        } else {
            // ================= layer 2 (has slack) =================
            const int r2 = (p > 0) ? (use_hist ? (p - 1) : ((p - 1) & 1)) : 0;
            const u32 want2 = (p >= 2) ? pw : 0u;

            { int gd = 0;
              while (lds_ld(&flag1) < pw + 1) { if (++gd > GLDS) break; } }
            const u32* rb = h1r + rdofs;
            uint4 h0 = *(const uint4*)(rb + 0),  h1v = *(const uint4*)(rb + 4);
            uint4 h2v = *(const uint4*)(rb + 8), h3v = *(const uint4*)(rb + 12);
            uint4 h4v = *(const uint4*)(rb + 16), h5v = *(const uint4*)(rb + 20);
            uint4 h6v = *(const uint4*)(rb + 24), h7v = *(const uint4*)(rb + 28);
            LGKM0();
            if (lane == 0) lds_add(&done1, 1);

            if (wave == 4) {
                PK8 pk = poll16(h2t + (size_t)r2 * 1024 + (lane << 4), want2);
                { int gd = 0;
                  while (lds_ld(&done2) < 3u * pw) { if (++gd > GLDS) break; } }
                *(uint4*)(h2r + wrofs)     = pk.a;
                *(uint4*)(h2r + wrofs + 4) = pk.b;
                LGKM0();
                if (lane == 0) lds_st(&flag2, pw + 1);
            }

            // W2 . h1 while h2 relay lands
            float e0 = (c16 == 0) ? bsum2 : 0.0f, e1 = 0.0f;
            const int idx2 = tid - 256;
            D4(e0, e1, h0, w23lds[0*256 + idx2]);
            D4(e0, e1, h1v, w23lds[1*256 + idx2]);
            D4(e0, e1, h2v, w23lds[2*256 + idx2]);
            D4(e0, e1, h3v, w23lds[3*256 + idx2]);
            D4(e0, e1, h4v, w23lds[4*256 + idx2]);
            D4(e0, e1, h5v, w23lds[5*256 + idx2]);
            D4(e0, e1, h6v, w23lds[6*256 + idx2]);
            D4(e0, e1, h7v, w23lds[7*256 + idx2]);

            if (wave != 4) {
                int gd = 0;
                while (lds_ld(&flag2) < pw + 1) { if (++gd > GLDS) break; }
            }
            const u32* gb = h2r + rdofs;
            uint4 q0 = *(const uint4*)(gb + 0),  q1 = *(const uint4*)(gb + 4);
            uint4 q2 = *(const uint4*)(gb + 8),  q3 = *(const uint4*)(gb + 12);
            uint4 q4 = *(const uint4*)(gb + 16), q5 = *(const uint4*)(gb + 20);
            uint4 q6 = *(const uint4*)(gb + 24), q7 = *(const uint4*)(gb + 28);
            if (wave != 4) { LGKM0(); if (lane == 0) lds_add(&done2, 1); }

            D4(e0, e1, q0, w23lds[8*256 + idx2]);
            D4(e0, e1, q1, w23lds[9*256 + idx2]);
            D4(e0, e1, q2, w23lds[10*256 + idx2]);
            D4(e0, e1, q3, w23lds[11*256 + idx2]);
            D4(e0, e1, q4, w23lds[12*256 + idx2]);
            D4(e0, e1, q5, w23lds[13*256 + idx2]);
            D4(e0, e1, q6, w23lds[14*256 + idx2]);
            D4(e0, e1, q7, w23lds[15*256 + idx2]);

            float s = e0 + e1;
            s += __shfl_xor(s, 1); s += __shfl_xor(s, 2);
            s += __shfl_xor(s, 4); s += __shfl_xor(s, 8);
            float sB = __shfl_xor(s, 16);
            float sC = __shfl_xor(s, 32);
            float sD = __shfl_xor(sB, 32);
            float iv = sigmoid_f(s), fv = sigmoid_f(sB);
            float gv = tanh_f(sC),  ov = sigmoid_f(sD);
            if (p >= 1) {
                cst = fv * cst + iv * gv;
                float hv = ov * tanh_f(cst);
                if (lane == 0) {
                    const int wr = use_hist ? p : (p & 1);
                    st_pair(h2t + (size_t)wr * 1024 + unit, hv, pw + 1);
                }
            }

            // fallback out-path (no hist): WG0 wave4 computes out(p-2)
            if (!use_hist && wg == 0 && wave == 4 && p >= 2) {
                const u32* pb = h2r + wrofs;   // this lane's 16 h2 elems
                uint4 ra = *(const uint4*)(pb), rc = *(const uint4*)(pb + 4);
                const int u0 = lane << 4;
                float p0 = 0.f, p1 = 0.f;
                #define FOUT(uu, base) do { U32H2 z; z.u = (uu); \
                    float v0 = (float)z.g.x, v1 = (float)z.g.y; \
                    p0 = fmaf(v0, Wout[(base)], p0);  p0 = fmaf(v1, Wout[(base)+1], p0); \
                    p1 = fmaf(v0, Wout[1024+(base)], p1); p1 = fmaf(v1, Wout[1024+(base)+1], p1); \
                } while (0)
                FOUT(ra.x, u0+0);  FOUT(ra.y, u0+2);  FOUT(ra.z, u0+4);  FOUT(ra.w, u0+6);
                FOUT(rc.x, u0+8);  FOUT(rc.y, u0+10); FOUT(rc.z, u0+12); FOUT(rc.w, u0+14);
                #pragma unroll
                for (int m = 1; m < 64; m <<= 1) {
                    p0 += __shfl_xor(p0, m); p1 += __shfl_xor(p1, m);
                }
                if (lane == 0) {
                    out[2*(p-2)+0] = p0 + bout[0];
                    out[2*(p-2)+1] = p1 + bout[1];
                }
            }
        }
    }

    // ---- epilogue ----
    if (use_hist) {
        const float2 wo0 = *(const float2*)(Wout + (tid << 1));
        const float2 wo1 = *(const float2*)(Wout + HID + (tid << 1));
        const float bo0 = bout[0], bo1 = bout[1];
        for (int i = 0; i < 16; ++i) {
            const int t = (wg << 4) + i;
            const u64* hp = h2t + (size_t)(t + 1) * 1024 + (tid << 1);
            const u32 want = (u32)(t + 2);
            u64 va, vb; int guard = 0;
            for (;;) {
                va = ld_pair(hp); vb = ld_pair(hp + 1);
                if ((PTAG(va) == want) && (PTAG(vb) == want)) break;
                if (++guard > GPOLL) break;
            }
            float h0 = PVAL(va), h1v = PVAL(vb);
            float q0 = wo0.x * h0 + wo0.y * h1v;
            float q1 = wo1.x * h0 + wo1.y * h1v;
            #pragma unroll
            for (int m = 1; m < 64; m <<= 1) {
                q0 += __shfl_xor(q0, m); q1 += __shfl_xor(q1, m);
            }
            if (lane == 0) { red0[wave] = q0; red1[wave] = q1; }
            __syncthreads();
            if (tid == 0) {
                float o0 = bo0, o1 = bo1;
                #pragma unroll
                for (int w = 0; w < 8; ++w) { o0 += red0[w]; o1 += red1[w]; }
                out[2*t+0] = o0; out[2*t+1] = o1;
            }
            __syncthreads();
        }
    } else if (wg == 0 && wave == 4) {
        // final out[T-1]: h2(T-1) in parity row T&1, tag T+1, f32 pairs
        const u64* bp = h2t + (size_t)(TSTEPS & 1) * 1024 + (lane << 4);
        const u32 want = (u32)(TSTEPS + 1);
        u64 t0,t1,t2,t3,t4,t5,t6,t7,t8,t9,tA,tB,tC,tD,tE,tF;
        int guard = 0;
        for (;;) {
            t0=ld_pair(bp+0);  t1=ld_pair(bp+1);  t2=ld_pair(bp+2);  t3=ld_pair(bp+3);
            t4=ld_pair(bp+4);  t5=ld_pair(bp+5);  t6=ld_pair(bp+6);  t7=ld_pair(bp+7);
            t8=ld_pair(bp+8);  t9=ld_pair(bp+9);  tA=ld_pair(bp+10); tB=ld_pair(bp+11);
            tC=ld_pair(bp+12); tD=ld_pair(bp+13); tE=ld_pair(bp+14); tF=ld_pair(bp+15);
            u32 ok = (PTAG(t0)==want)&(PTAG(t1)==want)&(PTAG(t2)==want)&(PTAG(t3)==want)
                   & (PTAG(t4)==want)&(PTAG(t5)==want)&(PTAG(t6)==want)&(PTAG(t7)==want)
                   & (PTAG(t8)==want)&(PTAG(t9)==want)&(PTAG(tA)==want)&(PTAG(tB)==want)
                   & (PTAG(tC)==want)&(PTAG(tD)==want)&(PTAG(tE)==want)&(PTAG(tF)==want);
            if (ok) break;
            if (++guard > GPOLL) break;
        }
        const int u0 = lane << 4;
        float p0 = 0.f, p1 = 0.f;
        #define FO2(T, i) do { float v = PVAL(T); \
            p0 = fmaf(v, Wout[u0+(i)], p0); p1 = fmaf(v, Wout[1024+u0+(i)], p1); } while (0)
        FO2(t0,0); FO2(t1,1); FO2(t2,2);  FO2(t3,3);  FO2(t4,4);  FO2(t5,5);
        FO2(t6,6); FO2(t7,7); FO2(t8,8);  FO2(t9,9);  FO2(tA,10); FO2(tB,11);
        FO2(tC,12); FO2(tD,13); FO2(tE,14); FO2(tF,15);
        #pragma unroll
        for (int m = 1; m < 64; m <<= 1) {
            p0 += __shfl_xor(p0, m); p1 += __shfl_xor(p1, m);
        }
        if (lane == 0) {
            out[2*(TSTEPS-1)+0] = p0 + bout[0];
            out[2*(TSTEPS-1)+1] = p1 + bout[1];
        }
    }
}

extern "C" void kernel_launch(void* const* d_in, const int* in_sizes, int n_in,
                              void* d_out, int out_size, void* d_ws, size_t ws_size,
                              hipStream_t stream)
{
    const float* x    = (const float*)d_in[0];
    const float* Wih1 = (const float*)d_in[1];
    const float* Whh1 = (const float*)d_in[2];
    const float* bih1 = (const float*)d_in[3];
    const float* bhh1 = (const float*)d_in[4];
    const float* Wih2 = (const float*)d_in[5];
    const float* Whh2 = (const float*)d_in[6];
    const float* bih2 = (const float*)d_in[7];
    const float* bhh2 = (const float*)d_in[8];
    const float* Wout = (const float*)d_in[9];
    const float* bout = (const float*)d_in[10];
    float* out = (float*)d_out;
    u64*   ws  = (u64*)d_ws;

    const int use_hist = (ws_size >= WS_NEED_BYTES) ? 1 : 0;

    (void)hipFuncSetAttribute((const void*)lstm_persistent,
                              hipFuncAttributeMaxDynamicSharedMemorySize,
                              DYN_LDS_BYTES);

    // zero h1 slots + h2 rows 0..1 (tags=0 == initial zero state; 0xAA
    // poison can never equal a wanted tag)
    (void)hipMemsetAsync(d_ws, 0, WS_ZERO_BYTES, stream);

    hipLaunchKernelGGL(lstm_persistent, dim3(NWG), dim3(TPB), DYN_LDS_BYTES,
                       stream,
                       x, Wih1, Whh1, bih1, bhh1,
                       Wih2, Whh2, bih2, bhh2,
                       Wout, bout, out, ws, use_hist);
}

// Round 12
// 14017.868 us; speedup vs baseline: 2.8076x; 2.8076x over previous
//
#include <hip/hip_runtime.h>
#include <math.h>

// LSTM_53171695124900: 2-layer LSTM, H=1024, I=64, O=2, T=4096.
// Round-12 = r10's proven distributed poll protocol + r11's proven in-wave
// gate combine, minus r11's failure modes (wave0 poll16 relay -> 4x FETCH,
// done-counters, 16-u64 spill).
//   waves 0-3 = layer-1 unit w: lane = gate(2b) x chunk(4b), 64 elems/lane.
//   waves 4-7 = layer-2 unit w-4: W2.h1 + W3.h2.
//   Every thread polls its OWN tagged pairs from IC (h1: 2 pairs/thread by
//   all; h2: 4 pairs/thread by layer-2 threads, early-read/verify-late).
//   2 wave-uniform barriers/phase: S1 (h1s staged), S2 (h2s staged; h1
//   published BEFORE S2 -> early publish slack preserved).
//   Gate combine via shfl_xor(16,32) in-wave (r11-proven); no g1/g2 LDS.
//   All weights f16 in LDS ([j*256+idx] layout, measured 0 conflicts).
//   IC protocol/tags/memset/epilogue byte-equivalent to r6-r10 (proven).

#define HID 1024
#define DIN 64
#define TSTEPS 4096
#define NWG 256
#define TPB 512

typedef unsigned long long u64;
typedef unsigned int u32;
typedef _Float16 f16x2 __attribute__((ext_vector_type(2)));
typedef __fp16   g16x2 __attribute__((ext_vector_type(2)));

// ws layout in u64: [0,2048) h1 pairs (2 slots x 1024); [2048,...) h2 rows
#define H2_OFF 2048
#define WS_NEED_U64 (2048ull + 4097ull * 1024ull)
#define WS_NEED_BYTES (WS_NEED_U64 * 8ull)
#define WS_ZERO_BYTES 32768

// dynamic LDS: W1 32KB | W2+W3 64KB | h1s 576 u32 | h2s 576 u32
#define W1_OFF 0
#define W23_OFF 32768
#define H1S_OFF (32768 + 65536)
#define H2S_OFF (H1S_OFF + 576 * 4)
#define DYN_LDS_BYTES (H2S_OFF + 576 * 4)   // 102912 B

#define GPOLL (1 << 17)

__device__ __forceinline__ float sigmoid_f(float v) {
    return 1.0f / (1.0f + __expf(-v));
}
__device__ __forceinline__ float tanh_f(float v) {
    return 2.0f / (1.0f + __expf(-2.0f * v)) - 1.0f;
}

__device__ __forceinline__ void st_pair(u64* p, float h, u32 tag) {
    u64 pk = ((u64)tag << 32) | (u64)__float_as_uint(h);
    __hip_atomic_store(p, pk, __ATOMIC_RELAXED, __HIP_MEMORY_SCOPE_AGENT);
}
__device__ __forceinline__ u64 ld_pair(const u64* p) {
    return __hip_atomic_load(p, __ATOMIC_RELAXED, __HIP_MEMORY_SCOPE_AGENT);
}
#define PTAG(v) ((u32)((v) >> 32))
#define PVAL(v) (__uint_as_float((u32)(v)))

union U32H2 { u32 u; f16x2 h; g16x2 g; };
__device__ __forceinline__ u32 pk2(float a, float b) {
    U32H2 t; t.g = __builtin_amdgcn_cvt_pkrtz(a, b); return t.u;
}
__device__ __forceinline__ float dot2f(u32 a, u32 b, float c) {
    U32H2 x, y; x.u = a; y.u = b;
    return __builtin_amdgcn_fdot2(x.h, y.h, c, false);
}
__device__ __forceinline__ float lo16f(u32 a) { U32H2 z; z.u = a; return (float)z.g.x; }
__device__ __forceinline__ float hi16f(u32 a) { U32H2 z; z.u = a; return (float)z.g.y; }

// uint4(f16x8) . uint4(f16x8) -> two f32 accs
#define D4(acc0, acc1, HV, WV) do { \
    acc0 = dot2f((HV).x, (WV).x, acc0); acc1 = dot2f((HV).y, (WV).y, acc1); \
    acc0 = dot2f((HV).z, (WV).z, acc0); acc1 = dot2f((HV).w, (WV).w, acc1); \
} while (0)

__global__ void
__attribute__((amdgpu_flat_work_group_size(TPB, TPB), amdgpu_waves_per_eu(2, 2)))
lstm_persistent(
    const float* __restrict__ x,
    const float* __restrict__ Wih1, const float* __restrict__ Whh1,
    const float* __restrict__ bih1, const float* __restrict__ bhh1,
    const float* __restrict__ Wih2, const float* __restrict__ Whh2,
    const float* __restrict__ bih2, const float* __restrict__ bhh2,
    const float* __restrict__ Wout, const float* __restrict__ bout,
    float* __restrict__ out, u64* __restrict__ ws, int use_hist)
{
    const int wg   = blockIdx.x;
    const int tid  = threadIdx.x;
    const int wave = tid >> 6;
    const int lane = tid & 63;
    const int gidx = lane >> 4;          // gate 0..3 (i,f,g,o)
    const int c16  = lane & 15;          // 64-elem chunk
    const int l2   = (wave >= 4);
    const int unit = (wg << 2) + (l2 ? wave - 4 : wave);
    const int row  = gidx * HID + unit;
    const int idx2 = tid - 256;          // layer-2 thread index (>=0 iff l2)

    u64* h1t = ws;
    u64* h2t = ws + H2_OFF;

    extern __shared__ __align__(16) char smem[];
    uint4* w1lds  = (uint4*)(smem + W1_OFF);    // [j*256 + tid], tid<256
    uint4* w23lds = (uint4*)(smem + W23_OFF);   // [j*256 + idx2]
    u32*   h1s    = (u32*)(smem + H1S_OFF);     // padded stride-36 rows
    u32*   h2s    = (u32*)(smem + H2S_OFF);

    __shared__ float red0[8], red1[8];

    // ---- one-time weight staging (each thread packs its OWN fragment) ----
    if (!l2) {
        const float* src = Whh1 + (size_t)row * HID + (c16 << 6);
        #pragma unroll
        for (int j = 0; j < 8; ++j) {
            float4 qa = *(const float4*)(src + 8*j);
            float4 qb = *(const float4*)(src + 8*j + 4);
            w1lds[j*256 + tid] = make_uint4(pk2(qa.x,qa.y), pk2(qa.z,qa.w),
                                            pk2(qb.x,qb.y), pk2(qb.z,qb.w));
        }
    } else {
        const float* s2 = Wih2 + (size_t)row * HID + (c16 << 6);
        const float* s3 = Whh2 + (size_t)row * HID + (c16 << 6);
        #pragma unroll
        for (int j = 0; j < 8; ++j) {
            float4 qa = *(const float4*)(s2 + 8*j);
            float4 qb = *(const float4*)(s2 + 8*j + 4);
            w23lds[j*256 + idx2] = make_uint4(pk2(qa.x,qa.y), pk2(qa.z,qa.w),
                                              pk2(qb.x,qb.y), pk2(qb.z,qb.w));
        }
        #pragma unroll
        for (int j = 0; j < 8; ++j) {
            float4 qa = *(const float4*)(s3 + 8*j);
            float4 qb = *(const float4*)(s3 + 8*j + 4);
            w23lds[(8+j)*256 + idx2] = make_uint4(pk2(qa.x,qa.y), pk2(qa.z,qa.w),
                                                  pk2(qb.x,qb.y), pk2(qb.z,qb.w));
        }
    }

    const float bsum = l2 ? (bih2[row] + bhh2[row]) : (bih1[row] + bhh1[row]);
    const float4 wx = *(const float4*)(Wih1 + (size_t)row * DIN + (c16 << 2));

    // h staging indices: u32 m -> 36*(m>>5) + (m&31)  (2-way max conflicts)
    const int sd1 = 36 * (tid >> 5) + (tid & 31);         // h1s: u32 idx = tid
    const int m2  = idx2 << 1;                            // h2s: 2 u32 / thread
    const int sd2 = 36 * (m2 >> 5) + (m2 & 31);
    const int rb  = 36 * c16;                             // read base

    float cst = 0.0f;   // c1 (waves 0-3) / c2 (waves 4-7), valid on lane 0

    __syncthreads();    // weights staged

    for (int p = 0; p <= TSTEPS; ++p) {
        const u32 pw = (u32)p;

        // ---- poll own h1 pairs (tag p; published early in phase p-1) ----
        const u64* h1p = h1t + (size_t)(p & 1) * 1024 + (tid << 1);
        u64 v1a, v1b;
        {
            int gd = 0;
            for (;;) {
                v1a = ld_pair(h1p); v1b = ld_pair(h1p + 1);
                if ((PTAG(v1a) == pw) & (PTAG(v1b) == pw)) break;
                if (++gd > GPOLL) break;  // hang insurance only
            }
        }

        // layer-2: early h2 reads (verified after the W2 dot)
        const int r2 = (p > 0) ? (use_hist ? (p - 1) : ((p - 1) & 1)) : 0;
        const u32 want2 = (p >= 2) ? pw : 0u;
        const u64* h2p = h2t + (size_t)r2 * 1024 + ((size_t)(l2 ? idx2 : 0) << 2);
        u64 y0 = 0, y1 = 0, y2 = 0, y3 = 0;
        if (l2) { y0 = ld_pair(h2p); y1 = ld_pair(h2p+1);
                  y2 = ld_pair(h2p+2); y3 = ld_pair(h2p+3); }

        h1s[sd1] = pk2(PVAL(v1a), PVAL(v1b));
        __syncthreads();   // S1: h1s staged

        float e0 = 0.f, e1 = 0.f;   // layer-2 partial acc (live across S2)
        if (!l2) {
            // ---- layer 1: full dot + in-wave combine + EARLY publish ----
            const u32* hb = h1s + rb;
            uint4 h0 = *(const uint4*)(hb+0),  h1v = *(const uint4*)(hb+4);
            uint4 h2v = *(const uint4*)(hb+8), h3v = *(const uint4*)(hb+12);
            uint4 h4v = *(const uint4*)(hb+16), h5v = *(const uint4*)(hb+20);
            uint4 h6v = *(const uint4*)(hb+24), h7v = *(const uint4*)(hb+28);
            float a0 = (c16 == 0) ? bsum : 0.f, a1 = 0.f;
            D4(a0, a1, h0,  w1lds[0*256 + tid]);
            D4(a0, a1, h1v, w1lds[1*256 + tid]);
            D4(a0, a1, h2v, w1lds[2*256 + tid]);
            D4(a0, a1, h3v, w1lds[3*256 + tid]);
            D4(a0, a1, h4v, w1lds[4*256 + tid]);
            D4(a0, a1, h5v, w1lds[5*256 + tid]);
            D4(a0, a1, h6v, w1lds[6*256 + tid]);
            D4(a0, a1, h7v, w1lds[7*256 + tid]);
            {
                const int tx = (p < TSTEPS) ? p : 0;
                const float4 xv = *(const float4*)(x + (size_t)tx * DIN + (c16 << 2));
                a0 = fmaf(wx.x, xv.x, a0); a1 = fmaf(wx.y, xv.y, a1);
                a0 = fmaf(wx.z, xv.z, a0); a1 = fmaf(wx.w, xv.w, a1);
            }
            float s = a0 + a1;
            s += __shfl_xor(s, 1); s += __shfl_xor(s, 2);
            s += __shfl_xor(s, 4); s += __shfl_xor(s, 8);
            float sB = __shfl_xor(s, 16);
            float sC = __shfl_xor(s, 32);
            float sD = __shfl_xor(sB, 32);
            // on gidx==0 lanes: s=i, sB=f, sC=g, sD=o  (r11-proven)
            float iv = sigmoid_f(s), fv = sigmoid_f(sB);
            float gv = tanh_f(sC),  ov = sigmoid_f(sD);
            cst = fv * cst + iv * gv;
            float hv = ov * tanh_f(cst);
            if (p < TSTEPS && lane == 0)
                st_pair(h1t + (size_t)((p + 1) & 1) * 1024 + unit, hv, pw + 1);
        } else {
            // ---- layer 2 part A: W2 . h1 while h2 lands; verify; stage ----
            const u32* hb = h1s + rb;
            uint4 h0 = *(const uint4*)(hb+0),  h1v = *(const uint4*)(hb+4);
            uint4 h2v = *(const uint4*)(hb+8), h3v = *(const uint4*)(hb+12);
            uint4 h4v = *(const uint4*)(hb+16), h5v = *(const uint4*)(hb+20);
            uint4 h6v = *(const uint4*)(hb+24), h7v = *(const uint4*)(hb+28);
            e0 = (c16 == 0) ? bsum : 0.f;
            D4(e0, e1, h0,  w23lds[0*256 + idx2]);
            D4(e0, e1, h1v, w23lds[1*256 + idx2]);
            D4(e0, e1, h2v, w23lds[2*256 + idx2]);
            D4(e0, e1, h3v, w23lds[3*256 + idx2]);
            D4(e0, e1, h4v, w23lds[4*256 + idx2]);
            D4(e0, e1, h5v, w23lds[5*256 + idx2]);
            D4(e0, e1, h6v, w23lds[6*256 + idx2]);
            D4(e0, e1, h7v, w23lds[7*256 + idx2]);
            {
                int gd = 0;
                while (!((PTAG(y0) == want2) & (PTAG(y1) == want2) &
                         (PTAG(y2) == want2) & (PTAG(y3) == want2))) {
                    y0 = ld_pair(h2p); y1 = ld_pair(h2p+1);
                    y2 = ld_pair(h2p+2); y3 = ld_pair(h2p+3);
                    if (++gd > GPOLL) break;  // hang insurance only
                }
            }
            h2s[sd2]     = pk2(PVAL(y0), PVAL(y1));
            h2s[sd2 + 1] = pk2(PVAL(y2), PVAL(y3));
        }
        __syncthreads();   // S2: h2s staged; h1 already published

        if (l2) {
            // ---- layer 2 part B: W3 . h2; combine; publish ----
            const u32* gb = h2s + rb;
            uint4 q0 = *(const uint4*)(gb+0),  q1 = *(const uint4*)(gb+4);
            uint4 q2 = *(const uint4*)(gb+8),  q3 = *(const uint4*)(gb+12);
            uint4 q4 = *(const uint4*)(gb+16), q5 = *(const uint4*)(gb+20);
            uint4 q6 = *(const uint4*)(gb+24), q7 = *(const uint4*)(gb+28);
            D4(e0, e1, q0, w23lds[8*256  + idx2]);
            D4(e0, e1, q1, w23lds[9*256  + idx2]);
            D4(e0, e1, q2, w23lds[10*256 + idx2]);
            D4(e0, e1, q3, w23lds[11*256 + idx2]);
            D4(e0, e1, q4, w23lds[12*256 + idx2]);
            D4(e0, e1, q5, w23lds[13*256 + idx2]);
            D4(e0, e1, q6, w23lds[14*256 + idx2]);
            D4(e0, e1, q7, w23lds[15*256 + idx2]);
            float s = e0 + e1;
            s += __shfl_xor(s, 1); s += __shfl_xor(s, 2);
            s += __shfl_xor(s, 4); s += __shfl_xor(s, 8);
            float sB = __shfl_xor(s, 16);
            float sC = __shfl_xor(s, 32);
            float sD = __shfl_xor(sB, 32);
            float iv = sigmoid_f(s), fv = sigmoid_f(sB);
            float gv = tanh_f(sC),  ov = sigmoid_f(sD);
            if (p >= 1) {
                cst = fv * cst + iv * gv;
                float hv = ov * tanh_f(cst);
                if (lane == 0) {
                    const int wr = use_hist ? p : (p & 1);
                    st_pair(h2t + (size_t)wr * 1024 + unit, hv, pw + 1);
                }
            }
            // fallback out-path (no hist): WG0 wave4 computes out(p-2) from h2s
            if (!use_hist && wg == 0 && wave == 4 && p >= 2) {
                const int mb = 36 * (lane >> 2) + 8 * (lane & 3);  // 8 u32
                uint4 ra = *(const uint4*)(h2s + mb);
                uint4 rc = *(const uint4*)(h2s + mb + 4);
                const int u0 = lane << 4;
                float p0 = 0.f, p1 = 0.f;
                #define FOUT(U, base) do { \
                    float v0 = lo16f(U), v1 = hi16f(U); \
                    p0 = fmaf(v0, Wout[(base)], p0);       p0 = fmaf(v1, Wout[(base)+1], p0); \
                    p1 = fmaf(v0, Wout[1024+(base)], p1);  p1 = fmaf(v1, Wout[1024+(base)+1], p1); \
                } while (0)
                FOUT(ra.x, u0+0);  FOUT(ra.y, u0+2);  FOUT(ra.z, u0+4);  FOUT(ra.w, u0+6);
                FOUT(rc.x, u0+8);  FOUT(rc.y, u0+10); FOUT(rc.z, u0+12); FOUT(rc.w, u0+14);
                #pragma unroll
                for (int m = 1; m < 64; m <<= 1) {
                    p0 += __shfl_xor(p0, m); p1 += __shfl_xor(p1, m);
                }
                if (lane == 0) {
                    out[2*(p-2)+0] = p0 + bout[0];
                    out[2*(p-2)+1] = p1 + bout[1];
                }
            }
        }
    }

    // ---- epilogue ----
    if (use_hist) {
        const float2 wo0 = *(const float2*)(Wout + (tid << 1));
        const float2 wo1 = *(const float2*)(Wout + HID + (tid << 1));
        const float bo0 = bout[0], bo1 = bout[1];
        for (int i = 0; i < 16; ++i) {
            const int t = (wg << 4) + i;
            const u64* hp = h2t + (size_t)(t + 1) * 1024 + (tid << 1);
            const u32 want = (u32)(t + 2);
            u64 va, vb; int guard = 0;
            for (;;) {
                va = ld_pair(hp); vb = ld_pair(hp + 1);
                if ((PTAG(va) == want) && (PTAG(vb) == want)) break;
                if (++guard > GPOLL) break;
            }
            float h0 = PVAL(va), h1v = PVAL(vb);
            float q0 = wo0.x * h0 + wo0.y * h1v;
            float q1 = wo1.x * h0 + wo1.y * h1v;
            #pragma unroll
            for (int m = 1; m < 64; m <<= 1) {
                q0 += __shfl_xor(q0, m); q1 += __shfl_xor(q1, m);
            }
            if (lane == 0) { red0[wave] = q0; red1[wave] = q1; }
            __syncthreads();
            if (tid == 0) {
                float o0 = bo0, o1 = bo1;
                #pragma unroll
                for (int w = 0; w < 8; ++w) { o0 += red0[w]; o1 += red1[w]; }
                out[2*t+0] = o0; out[2*t+1] = o1;
            }
            __syncthreads();
        }
    } else if (wg == 0 && wave == 4) {
        // final out[T-1]: h2(T-1) in parity row TSTEPS&1 = 0, tag TSTEPS+1
        const u64* bp = h2t + (size_t)(TSTEPS & 1) * 1024 + ((size_t)lane << 4);
        const u32 want = (u32)(TSTEPS + 1);
        float p0 = 0.f, p1 = 0.f;
        const int u0 = lane << 4;
        #pragma unroll
        for (int i = 0; i < 16; ++i) {
            u64 v; int guard = 0;
            for (;;) {
                v = ld_pair(bp + i);
                if (PTAG(v) == want) break;
                if (++guard > GPOLL) break;
            }
            float hv = PVAL(v);
            p0 = fmaf(hv, Wout[u0 + i], p0);
            p1 = fmaf(hv, Wout[1024 + u0 + i], p1);
        }
        #pragma unroll
        for (int m = 1; m < 64; m <<= 1) {
            p0 += __shfl_xor(p0, m); p1 += __shfl_xor(p1, m);
        }
        if (lane == 0) {
            out[2*(TSTEPS-1)+0] = p0 + bout[0];
            out[2*(TSTEPS-1)+1] = p1 + bout[1];
        }
    }
}

extern "C" void kernel_launch(void* const* d_in, const int* in_sizes, int n_in,
                              void* d_out, int out_size, void* d_ws, size_t ws_size,
                              hipStream_t stream)
{
    const float* x    = (const float*)d_in[0];
    const float* Wih1 = (const float*)d_in[1];
    const float* Whh1 = (const float*)d_in[2];
    const float* bih1 = (const float*)d_in[3];
    const float* bhh1 = (const float*)d_in[4];
    const float* Wih2 = (const float*)d_in[5];
    const float* Whh2 = (const float*)d_in[6];
    const float* bih2 = (const float*)d_in[7];
    const float* bhh2 = (const float*)d_in[8];
    const float* Wout = (const float*)d_in[9];
    const float* bout = (const float*)d_in[10];
    float* out = (float*)d_out;
    u64*   ws  = (u64*)d_ws;

    const int use_hist = (ws_size >= WS_NEED_BYTES) ? 1 : 0;

    (void)hipFuncSetAttribute((const void*)lstm_persistent,
                              hipFuncAttributeMaxDynamicSharedMemorySize,
                              DYN_LDS_BYTES);

    // zero h1 slots + h2 rows 0..1 (tags=0 == initial zero state; 0xAA
    // poison can never equal a wanted tag)
    (void)hipMemsetAsync(d_ws, 0, WS_ZERO_BYTES, stream);

    hipLaunchKernelGGL(lstm_persistent, dim3(NWG), dim3(TPB), DYN_LDS_BYTES,
                       stream,
                       x, Wih1, Whh1, bih1, bhh1,
                       Wih2, Whh2, bih2, bhh2,
                       Wout, bout, out, ws, use_hist);
}